// Round 2
// baseline (746.565 us; speedup 1.0000x reference)
//
#include <hip/hip_runtime.h>
#include <hip/hip_bf16.h>
#include <hip/hip_fp16.h>

// Problem: y[b,s,o] = sum_i x[b,s,i] * w[o,i] + bias[o]
//   w = weight_high + fp32(weight_medium) + (~high & ~medium) * weight_low * low_scale
// M = 4*2048 = 8192, N = 4096, K = 4096.
// Strategy: detect harness dtype normalization (fp16->fp32? bool->int32?),
// dequant w -> bf16 (ws), cvt x -> bf16 (ws), then m97-style 128x128x32
// bf16 MFMA GEMM with global_load_lds(16B) staging.

#define M_DIM 8192
#define N_DIM 4096
#define K_DIM 4096

typedef __attribute__((ext_vector_type(8))) short short8;
typedef __attribute__((ext_vector_type(4))) float floatx4;
typedef __attribute__((ext_vector_type(8))) _Float16 half8;
typedef __attribute__((ext_vector_type(8))) unsigned char uchar8;
typedef __attribute__((ext_vector_type(4))) int intx4;

__device__ inline unsigned short f2bf(float f) {
    union { float f; unsigned u; } v; v.f = f;
    return (unsigned short)((v.u + 0x7fffu + ((v.u >> 16) & 1u)) >> 16);  // RNE
}

__device__ inline void async16(const void* g, const void* l) {
    __builtin_amdgcn_global_load_lds(
        (const __attribute__((address_space(1))) void*)g,
        (__attribute__((address_space(3))) void*)l,
        16, 0, 0);
}

// ---------- dtype-normalization probe ----------
// flags[0] = 1 iff weight_medium buffer is fp32 (else raw fp16)
// flags[1] = 1 iff mask buffers are 1-byte bools (else int32)
__global__ __launch_bounds__(256) void detect_kernel(const unsigned* __restrict__ wm_raw,
                                                     const unsigned* __restrict__ hm_raw,
                                                     int* __restrict__ flags) {
    __shared__ int s_f32cnt, s_maskbig;
    if (threadIdx.x == 0) { s_f32cnt = 0; s_maskbig = 0; }
    __syncthreads();
    union { unsigned u; float f; } w; w.u = wm_raw[threadIdx.x];
    float av = fabsf(w.f);
    if (av > 1e-4f && av < 1.0f) atomicAdd(&s_f32cnt, 1);   // fp16-as-fp32 reads land <1e-16
    if (hm_raw[threadIdx.x] > 1u) atomicAdd(&s_maskbig, 1); // int32 bools are only 0/1
    __syncthreads();
    if (threadIdx.x == 0) {
        flags[0] = (s_f32cnt >= 8) ? 1 : 0;
        flags[1] = (s_maskbig > 0) ? 1 : 0;
    }
}

// ---------- x fp32 -> bf16 ----------
__global__ __launch_bounds__(256) void cvt_x_kernel(const float* __restrict__ x,
                                                    unsigned short* __restrict__ o) {
    const int i = (blockIdx.x * 256 + threadIdx.x) * 8;
    floatx4 f0 = *(const floatx4*)(x + i);
    floatx4 f1 = *(const floatx4*)(x + i + 4);
    short8 s;
    s[0] = (short)f2bf(f0[0]); s[1] = (short)f2bf(f0[1]);
    s[2] = (short)f2bf(f0[2]); s[3] = (short)f2bf(f0[3]);
    s[4] = (short)f2bf(f1[0]); s[5] = (short)f2bf(f1[1]);
    s[6] = (short)f2bf(f1[2]); s[7] = (short)f2bf(f1[3]);
    *(short8*)(o + i) = s;
}

// ---------- w reconstruct -> bf16 ----------
__global__ __launch_bounds__(256) void build_w_kernel(
        const float* __restrict__ wh, const void* __restrict__ wm_raw,
        const int* __restrict__ wl, const void* __restrict__ hm_raw,
        const void* __restrict__ mm_raw, const float* __restrict__ scale_p,
        const int* __restrict__ flags, unsigned short* __restrict__ o) {
    const int i = (blockIdx.x * 256 + threadIdx.x) * 8;
    const float scale = *scale_p;
    const bool wm_f32  = flags[0] != 0;
    const bool mask_u8 = flags[1] != 0;

    floatx4 h0 = *(const floatx4*)(wh + i);
    floatx4 h1 = *(const floatx4*)(wh + i + 4);
    intx4  l0 = *(const intx4*)(wl + i);
    intx4  l1 = *(const intx4*)(wl + i + 4);

    float mv[8];
    if (wm_f32) {
        floatx4 m0 = *(const floatx4*)((const float*)wm_raw + i);
        floatx4 m1 = *(const floatx4*)((const float*)wm_raw + i + 4);
#pragma unroll
        for (int e = 0; e < 4; ++e) { mv[e] = m0[e]; mv[e + 4] = m1[e]; }
    } else {
        half8 m = *(const half8*)((const _Float16*)wm_raw + i);
#pragma unroll
        for (int e = 0; e < 8; ++e) mv[e] = (float)m[e];
    }

    int lowmask[8];
    if (mask_u8) {
        uchar8 a = *(const uchar8*)((const unsigned char*)hm_raw + i);
        uchar8 b = *(const uchar8*)((const unsigned char*)mm_raw + i);
#pragma unroll
        for (int e = 0; e < 8; ++e) lowmask[e] = (a[e] | b[e]) == 0;
    } else {
        intx4 a0 = *(const intx4*)((const int*)hm_raw + i);
        intx4 a1 = *(const intx4*)((const int*)hm_raw + i + 4);
        intx4 b0 = *(const intx4*)((const int*)mm_raw + i);
        intx4 b1 = *(const intx4*)((const int*)mm_raw + i + 4);
#pragma unroll
        for (int e = 0; e < 4; ++e) {
            lowmask[e]     = (a0[e] | b0[e]) == 0;
            lowmask[e + 4] = (a1[e] | b1[e]) == 0;
        }
    }

    short8 s;
#pragma unroll
    for (int e = 0; e < 8; ++e) {
        float v = (e < 4 ? h0[e] : h1[e - 4]) + mv[e];
        int   lw = (e < 4 ? l0[e] : l1[e - 4]);
        if (lowmask[e]) v += (float)lw * scale;
        s[e] = (short)f2bf(v);
    }
    *(short8*)(o + i) = s;
}

// ---------- GEMM: C[m,n] = sum_k A[m,k]*B[n,k] + bias[n] (A,B bf16, C fp32) ----------
__global__ __launch_bounds__(256) void gemm_kernel(
        const unsigned short* __restrict__ A,   // [M,K] bf16
        const unsigned short* __restrict__ Bw,  // [N,K] bf16
        const float* __restrict__ bias,
        float* __restrict__ out) {
    __shared__ unsigned short As[128 * 32];
    __shared__ unsigned short Bs[128 * 32];
    const int tid  = threadIdx.x;
    const int wave = tid >> 6, lane = tid & 63;
    const int bm0 = blockIdx.y * 128, bn0 = blockIdx.x * 128;
    const int wm = (wave >> 1) * 64, wn = (wave & 1) * 64;
    const int lrow = lane & 15, lquad = lane >> 4;

    floatx4 acc[4][4] = {};

    for (int k0 = 0; k0 < K_DIM; k0 += 32) {
        __syncthreads();
#pragma unroll
        for (int c = 0; c < 2; ++c) {
            const int lb  = wave * 2048 + c * 1024;   // wave-uniform byte offset in tile
            const int e   = (lb >> 1) + lane * 8;     // per-lane element in tile
            const int row = e >> 5, col = e & 31;
            async16(A  + (size_t)(bm0 + row) * K_DIM + k0 + col, (const char*)As + lb);
            async16(Bw + (size_t)(bn0 + row) * K_DIM + k0 + col, (const char*)Bs + lb);
        }
        __syncthreads();

        short8 af[4], bf[4];
#pragma unroll
        for (int i = 0; i < 4; ++i)
            af[i] = *(const short8*)&As[(wm + i * 16 + lrow) * 32 + lquad * 8];
#pragma unroll
        for (int j = 0; j < 4; ++j)
            bf[j] = *(const short8*)&Bs[(wn + j * 16 + lrow) * 32 + lquad * 8];
#pragma unroll
        for (int i = 0; i < 4; ++i)
#pragma unroll
            for (int j = 0; j < 4; ++j)
                acc[i][j] = __builtin_amdgcn_mfma_f32_16x16x32_bf16(af[i], bf[j], acc[i][j], 0, 0, 0);
    }

#pragma unroll
    for (int j = 0; j < 4; ++j) {
        const int col = bn0 + wn + j * 16 + lrow;
        const float bv = bias[col];
#pragma unroll
        for (int i = 0; i < 4; ++i) {
            const int row = bm0 + wm + i * 16 + lquad * 4;
#pragma unroll
            for (int r = 0; r < 4; ++r)
                out[(size_t)(row + r) * N_DIM + col] = acc[i][j][r] + bv;
        }
    }
}

// ---------- fallback: A staged from fp32 inline (small-ws path) ----------
__global__ __launch_bounds__(256) void gemm_fused_kernel(
        const float* __restrict__ X,            // [M,K] fp32
        const unsigned short* __restrict__ Bw,  // [N,K] bf16
        const float* __restrict__ bias,
        float* __restrict__ out) {
    __shared__ unsigned short As[128 * 32];
    __shared__ unsigned short Bs[128 * 32];
    const int tid  = threadIdx.x;
    const int wave = tid >> 6, lane = tid & 63;
    const int bm0 = blockIdx.y * 128, bn0 = blockIdx.x * 128;
    const int wm = (wave >> 1) * 64, wn = (wave & 1) * 64;
    const int lrow = lane & 15, lquad = lane >> 4;
    const int arow = tid >> 1, acol = (tid & 1) * 16;

    floatx4 acc[4][4] = {};

    for (int k0 = 0; k0 < K_DIM; k0 += 32) {
        __syncthreads();
#pragma unroll
        for (int c = 0; c < 2; ++c) {
            const int lb  = wave * 2048 + c * 1024;
            const int e   = (lb >> 1) + lane * 8;
            const int row = e >> 5, col = e & 31;
            async16(Bw + (size_t)(bn0 + row) * K_DIM + k0 + col, (const char*)Bs + lb);
        }
        {
            const float* g = X + (size_t)(bm0 + arow) * K_DIM + k0 + acol;
            floatx4 f0 = *(const floatx4*)(g);
            floatx4 f1 = *(const floatx4*)(g + 4);
            floatx4 f2 = *(const floatx4*)(g + 8);
            floatx4 f3 = *(const floatx4*)(g + 12);
            short8 s0, s1;
            s0[0]=(short)f2bf(f0[0]); s0[1]=(short)f2bf(f0[1]); s0[2]=(short)f2bf(f0[2]); s0[3]=(short)f2bf(f0[3]);
            s0[4]=(short)f2bf(f1[0]); s0[5]=(short)f2bf(f1[1]); s0[6]=(short)f2bf(f1[2]); s0[7]=(short)f2bf(f1[3]);
            s1[0]=(short)f2bf(f2[0]); s1[1]=(short)f2bf(f2[1]); s1[2]=(short)f2bf(f2[2]); s1[3]=(short)f2bf(f2[3]);
            s1[4]=(short)f2bf(f3[0]); s1[5]=(short)f2bf(f3[1]); s1[6]=(short)f2bf(f3[2]); s1[7]=(short)f2bf(f3[3]);
            *(short8*)&As[arow * 32 + acol]     = s0;
            *(short8*)&As[arow * 32 + acol + 8] = s1;
        }
        __syncthreads();

        short8 af[4], bf[4];
#pragma unroll
        for (int i = 0; i < 4; ++i)
            af[i] = *(const short8*)&As[(wm + i * 16 + lrow) * 32 + lquad * 8];
#pragma unroll
        for (int j = 0; j < 4; ++j)
            bf[j] = *(const short8*)&Bs[(wn + j * 16 + lrow) * 32 + lquad * 8];
#pragma unroll
        for (int i = 0; i < 4; ++i)
#pragma unroll
            for (int j = 0; j < 4; ++j)
                acc[i][j] = __builtin_amdgcn_mfma_f32_16x16x32_bf16(af[i], bf[j], acc[i][j], 0, 0, 0);
    }

#pragma unroll
    for (int j = 0; j < 4; ++j) {
        const int col = bn0 + wn + j * 16 + lrow;
        const float bv = bias[col];
#pragma unroll
        for (int i = 0; i < 4; ++i) {
            const int row = bm0 + wm + i * 16 + lquad * 4;
#pragma unroll
            for (int r = 0; r < 4; ++r)
                out[(size_t)(row + r) * N_DIM + col] = acc[i][j][r] + bv;
        }
    }
}

extern "C" void kernel_launch(void* const* d_in, const int* in_sizes, int n_in,
                              void* d_out, int out_size, void* d_ws, size_t ws_size,
                              hipStream_t stream) {
    const float*    x     = (const float*)d_in[0];
    const float*    wh    = (const float*)d_in[1];
    const void*     wmed  = d_in[2];           // fp32 or fp16 — detected on device
    const int*      wl    = (const int*)d_in[3];
    const void*     hm    = d_in[4];           // int32 or uint8 — detected on device
    const void*     mm    = d_in[5];
    const float*    scale = (const float*)d_in[6];
    const float*    bias  = (const float*)d_in[7];
    float*          out   = (float*)d_out;

    int*            flags = (int*)d_ws;                                   // 256 B reserved
    unsigned short* wbf   = (unsigned short*)((char*)d_ws + 256);         // 32 MB
    unsigned short* xbf   = (unsigned short*)((char*)d_ws + 256 + (size_t)N_DIM * K_DIM * 2);
    const size_t need_full = 256 + (size_t)N_DIM * K_DIM * 2 + (size_t)M_DIM * K_DIM * 2;

    detect_kernel<<<1, 256, 0, stream>>>((const unsigned*)wmed, (const unsigned*)hm, flags);
    build_w_kernel<<<N_DIM * K_DIM / 2048, 256, 0, stream>>>(wh, wmed, wl, hm, mm, scale, flags, wbf);

    dim3 grid(N_DIM / 128, M_DIM / 128);
    if (ws_size >= need_full) {
        cvt_x_kernel<<<M_DIM * K_DIM / 2048, 256, 0, stream>>>(x, xbf);
        gemm_kernel<<<grid, 256, 0, stream>>>(xbf, wbf, bias, out);
    } else {
        gemm_fused_kernel<<<grid, 256, 0, stream>>>(x, wbf, bias, out);
    }
}